// Round 10
// baseline (730.845 us; speedup 1.0000x reference)
//
#include <hip/hip_runtime.h>
#include <hip/hip_fp16.h>
#include <math.h>

#define HW 1024
#define EPSV 1e-5f

typedef unsigned int uint;
typedef unsigned short ushort;
typedef __attribute__((ext_vector_type(8))) short short8;
typedef __attribute__((ext_vector_type(8))) _Float16 half8;
typedef __attribute__((ext_vector_type(4))) float floatx4;

// ---------------- ws layout (float offsets), no aliasing ---------------------------
static const size_t BOFF = 0;         // 36864   fp16 Boff[tap][n32][c256]
static const size_t BD   = 36864;     // 147456  fp16 Bd[oc][tap*256+c]
static const size_t BQ   = 184320;    // 131072  bf16 Bq[par][kstep][quad][n][8]
static const size_t XT   = 315392;    // 2097152 fp16 xT[b][p][c]
static const size_t OFFB = 2412544;   // 524288  off [b][pix][32] fp32 (atomic)
static const size_t ST1  = 2936832;   // 2048: BN1 sum/sq, 8 stripes of 256
static const size_t ST2  = 2938880;   // 4096: BN2 sum/sq, 16 stripes of 256
static const size_t CTR  = 2942976;   // 32: phase counters (ints)
static const size_t YP   = 2943008;   // 4194304 floats = bf16 y_part[4][pix][oc]
static const size_t YSUM = 7137312;   // 1048576 floats = bf16 ysum[pix][oc]
static const size_t YBN  = 8185888;   // 1048576 floats = bf16 ybn[pix][oc]
static const size_t OB   = 9234464;   // 4194304 floats = bf16 O[b][par][pix][oc]
// total = 13428768 floats = 53.7 MB

__device__ inline ushort f2bf(float f) {
  uint u = __builtin_bit_cast(uint, f);
  uint r = (u + 0x7FFFu + ((u >> 16) & 1u)) >> 16;
  return (ushort)r;
}
__device__ inline float b2f(ushort u) {
  return __builtin_bit_cast(float, ((uint)u) << 16);
}

// device-scope phase barrier for a co-resident grid
__device__ __forceinline__ void gbar(int* ctr, int target) {
  __syncthreads();
  __threadfence();                               // release: drain + wb L2
  if (threadIdx.x == 0) {
    __hip_atomic_fetch_add(ctr, 1, __ATOMIC_ACQ_REL, __HIP_MEMORY_SCOPE_AGENT);
    while (__hip_atomic_load(ctr, __ATOMIC_RELAXED, __HIP_MEMORY_SCOPE_AGENT) < target)
      __builtin_amdgcn_s_sleep(8);
  }
  __syncthreads();
  __threadfence();                               // acquire: inv stale lines
}

// ---------------- 1. prep + xT + zero accumulators/off/counters --------------------
__global__ __launch_bounds__(256) void prep_xt_kernel(const float* __restrict__ x,
                                                      const float* __restrict__ w_off,
                                                      const float* __restrict__ w_dcn,
                                                      const float* __restrict__ w_up,
                                                      float* __restrict__ ws) {
  __shared__ float tile[64 * 65];
  int blk = blockIdx.x;
  int tid = threadIdx.x;
  if (blk < 1024) {
    int b = blk >> 6, pt = (blk >> 2) & 15, cc = blk & 3;
    int p0 = pt * 64, c0 = cc * 64;
    int pp = tid & 63, ci = tid >> 6;
#pragma unroll
    for (int it = 0; it < 16; ++it) {
      int c = it * 4 + ci;
      tile[c * 65 + pp] = x[((size_t)(b * 256 + c0 + c)) * HW + p0 + pp];
    }
    __syncthreads();
    int cp = tid & 31, pp2 = tid >> 5;
    uint* xtu = (uint*)(ws + XT);
#pragma unroll
    for (int it = 0; it < 8; ++it) {
      int p = it * 8 + pp2;
      __half2 h = __floats2half2_rn(tile[(2 * cp) * 65 + p], tile[(2 * cp + 1) * 65 + p]);
      xtu[(size_t)(b * 1024 + p0 + p) * 128 + cc * 32 + cp] = __builtin_bit_cast(uint, h);
    }
  } else if (blk < 3488) {
    int i = (blk - 1024) * 256 + tid;
    if (i < 73728) {
      int c = i & 255; int n = (i >> 8) & 31; int tap = i >> 13;
      float v = (n < 27) ? w_off[((size_t)n * 256 + c) * 9 + tap] : 0.f;
      ((__half*)(ws + BOFF))[i] = __float2half(v);
    } else if (i < 73728 + 294912) {
      int d = i - 73728;            // d = oc*2304 + tap*256 + c
      int oc = d / 2304; int k = d % 2304;
      int tap = k >> 8; int c = k & 255;
      ((__half*)(ws + BD))[d] = __float2half(w_dcn[((size_t)oc * 256 + c) * 9 + tap]);
    } else if (i < 73728 + 294912 + 262144) {
      int d = i - (73728 + 294912);
      int j = d & 7; int n = (d >> 3) & 127; int quad = (d >> 10) & 3;
      int kstep = (d >> 12) & 15; int par = d >> 16;
      int k = kstep * 32 + quad * 8 + j;
      int t4 = k >> 7; int c = k & 127;
      int ty = t4 >> 1, tx = t4 & 1;
      int pu = par >> 1, pv = par & 1;
      int ky = (1 - pu) + 2 * ty, kx = (1 - pv) + 2 * tx;
      float v = w_up[((size_t)c * 128 + n) * 16 + ky * 4 + kx];
      ((ushort*)(ws + BQ))[d] = f2bf(v);
    }
  } else {
    int i = (blk - 3488) * 256 + tid;
    if (i < 6176) ws[ST1 + i] = 0.f;                           // ST1+ST2+CTR
    else if (i < 6176 + 524288) ws[OFFB + (i - 6176)] = 0.f;   // off accumulator
  }
}

// ---------------- 2. mega: offconv -> deform -> yred -> ybn -> deconv -> bnout -----
__global__ __launch_bounds__(256) void mega_kernel(const float* __restrict__ b_off,
                                                   const float* __restrict__ b_dcn,
                                                   const float* __restrict__ g1,
                                                   const float* __restrict__ bt1,
                                                   const float* __restrict__ g2,
                                                   const float* __restrict__ bt2,
                                                   float* __restrict__ ws,
                                                   float* __restrict__ out) {
  __shared__ __attribute__((aligned(16))) char smem[27648];
  __shared__ float scsS[128], shsS[128];
  const __half* xt   = (const __half*)(ws + XT);
  const __half* boff = (const __half*)(ws + BOFF);
  const __half* bd   = (const __half*)(ws + BD);
  const ushort* bq   = (const ushort*)(ws + BQ);
  float* off = ws + OFFB;
  float* st1 = ws + ST1;
  float* st2 = ws + ST2;
  int*   ctr = (int*)(ws + CTR);
  ushort* yp   = (ushort*)(ws + YP);
  ushort* ysum = (ushort*)(ws + YSUM);
  ushort* ybn  = (ushort*)(ws + YBN);
  ushort* Ob   = (ushort*)(ws + OB);

  int blk = blockIdx.x;
  int tid = threadIdx.x;
  int wid = tid >> 6, lane = tid & 63, lr = lane & 15, quad = lane >> 4;

  // ===== phase 1: offset conv (2 units), atomic raw accumulate =====
  {
    short* As = (short*)smem;
    short* Bs = (short*)(smem + 8448);
    int m_w = (wid & 1) * 16, n_w = (wid >> 1) * 16;
    int arow = tid >> 3, aseg = tid & 7;
    for (int u = 0; u < 2; ++u) {
      int ublk = blk * 2 + u;
      int pt = ublk & 31, cs = (ublk >> 5) & 1, b = ublk >> 6;
      int P0 = pt * 32;
      int pix = P0 + arow; int h = pix >> 5, w = pix & 31;
      floatx4 acc = (floatx4)0.f;
      for (int tap = 0; tap < 9; ++tap) {
        int ty = tap / 3, tx = tap % 3;
        int yy = h + ty - 1, xx = w + tx - 1;
        bool valid = (yy >= 0) && (yy < 32) && (xx >= 0) && (xx < 32);
        int pos = min(max(yy, 0), 31) * 32 + min(max(xx, 0), 31);
        const float4* ga = (const float4*)(xt + ((size_t)(b * 1024 + pos)) * 256 + cs * 128 + aseg * 16);
        float4 a0 = ga[0], a1 = ga[1];
        if (!valid) { a0 = make_float4(0.f, 0.f, 0.f, 0.f); a1 = a0; }
        const float4* gb = (const float4*)(boff + ((size_t)(tap * 32 + arow)) * 256 + cs * 128 + aseg * 16);
        float4 b0 = gb[0], b1 = gb[1];
        __syncthreads();
        float4* qa = (float4*)(As + arow * 132 + aseg * 16);
        qa[0] = a0; qa[1] = a1;
        float4* qb = (float4*)(Bs + arow * 132 + aseg * 16);
        qb[0] = b0; qb[1] = b1;
        __syncthreads();
#pragma unroll
        for (int k2 = 0; k2 < 4; ++k2) {
          half8 af = *(const half8*)(As + (m_w + lr) * 132 + k2 * 32 + quad * 8);
          half8 bf = *(const half8*)(Bs + (n_w + lr) * 132 + k2 * 32 + quad * 8);
          acc = __builtin_amdgcn_mfma_f32_16x16x32_f16(af, bf, acc, 0, 0, 0);
        }
      }
      int n = n_w + lr;
#pragma unroll
      for (int r = 0; r < 4; ++r) {
        int m = m_w + quad * 4 + r;
        atomicAdd(&off[((size_t)(b * 1024 + P0 + m)) * 32 + n], acc[r]);
      }
    }
  }
  gbar(&ctr[0], 512);

  // ===== phase 2: deformable conv (2 units), bf16 partials =====
  {
    short* As = (short*)smem;             // 64 x 72
    short* Bs = (short*)(smem + 9216);    // 128 x 72
    int m_w = (wid & 1) * 32, n_w = (wid >> 1) * 64;
    int pix_l = tid >> 2, cseg = tid & 3;
    int ocb = tid >> 1, seg = tid & 1;
    for (int u = 0; u < 2; ++u) {
      int ublk = blk * 2 + u;
      int ptile = ublk & 15, cs = (ublk >> 4) & 3, b = ublk >> 6;
      int P0 = ptile * 64;
      int pix = P0 + pix_l;
      int h = pix >> 5, w = pix & 31;
      const float* offb = off + (size_t)(b * 1024 + pix) * 32;
      const __half* xb = xt + (size_t)b * 1024 * 256 + cs * 64 + cseg * 16;
      const __half* bdr = bd + (size_t)ocb * 2304 + cs * 64 + seg * 32;

      floatx4 acc[2][4];
#pragma unroll
      for (int mi = 0; mi < 2; ++mi)
#pragma unroll
        for (int ni = 0; ni < 4; ++ni) acc[mi][ni] = (floatx4)0.f;

      for (int tap = 0; tap < 9; ++tap) {
        float dy = offb[2 * tap] + b_off[2 * tap];
        float dx = offb[2 * tap + 1] + b_off[2 * tap + 1];
        float mraw = offb[18 + tap] + b_off[18 + tap];
        float mm = 1.f / (1.f + __expf(-mraw));
        float py = (float)(h + tap / 3 - 1) + dy;
        float px = (float)(w + tap % 3 - 1) + dx;
        float y0f = floorf(py), x0f = floorf(px);
        float wy = py - y0f, wx = px - x0f;
        int y0 = (int)y0f, x0 = (int)x0f;
        float cw[4] = {(1.f - wy) * (1.f - wx), (1.f - wy) * wx, wy * (1.f - wx), wy * wx};
        uint4 q[4][2];
        __half2 w2[4];
#pragma unroll
        for (int t = 0; t < 4; ++t) {
          int yy = y0 + (t >> 1), xx = x0 + (t & 1);
          bool v = (yy >= 0) && (yy <= 31) && (xx >= 0) && (xx <= 31);
          int yc = min(max(yy, 0), 31), xc = min(max(xx, 0), 31);
          const uint4* xr = (const uint4*)(xb + (size_t)(yc * 32 + xc) * 256);
          q[t][0] = xr[0]; q[t][1] = xr[1];
          w2[t] = __float2half2_rn(v ? cw[t] * mm : 0.f);
        }
        const float4* gb = (const float4*)(bdr + tap * 256);
        float4 b0 = gb[0], b1 = gb[1], b2 = gb[2], b3 = gb[3];

        __half2 hacc[8];
#pragma unroll
        for (int j = 0; j < 8; ++j) hacc[j] = __float2half2_rn(0.f);
#pragma unroll
        for (int t = 0; t < 4; ++t) {
          uint qa[8] = {q[t][0].x, q[t][0].y, q[t][0].z, q[t][0].w,
                        q[t][1].x, q[t][1].y, q[t][1].z, q[t][1].w};
#pragma unroll
          for (int j = 0; j < 8; ++j)
            hacc[j] = __hfma2(w2[t], __builtin_bit_cast(__half2, qa[j]), hacc[j]);
        }
        __syncthreads();
        {
          float4 f0, f1;
          f0.x = __builtin_bit_cast(float, hacc[0]);
          f0.y = __builtin_bit_cast(float, hacc[1]);
          f0.z = __builtin_bit_cast(float, hacc[2]);
          f0.w = __builtin_bit_cast(float, hacc[3]);
          f1.x = __builtin_bit_cast(float, hacc[4]);
          f1.y = __builtin_bit_cast(float, hacc[5]);
          f1.z = __builtin_bit_cast(float, hacc[6]);
          f1.w = __builtin_bit_cast(float, hacc[7]);
          float4* qa2 = (float4*)(As + pix_l * 72 + cseg * 16);
          qa2[0] = f0; qa2[1] = f1;
        }
        float4* qb = (float4*)(Bs + ocb * 72 + seg * 32);
        qb[0] = b0; qb[1] = b1; qb[2] = b2; qb[3] = b3;
        __syncthreads();
#pragma unroll
        for (int k2 = 0; k2 < 2; ++k2) {
          half8 af[2], bf[4];
#pragma unroll
          for (int mi = 0; mi < 2; ++mi)
            af[mi] = *(const half8*)(As + (m_w + mi * 16 + lr) * 72 + k2 * 32 + quad * 8);
#pragma unroll
          for (int ni = 0; ni < 4; ++ni)
            bf[ni] = *(const half8*)(Bs + (n_w + ni * 16 + lr) * 72 + k2 * 32 + quad * 8);
#pragma unroll
          for (int mi = 0; mi < 2; ++mi)
#pragma unroll
            for (int ni = 0; ni < 4; ++ni)
              acc[mi][ni] = __builtin_amdgcn_mfma_f32_16x16x32_f16(af[mi], bf[ni], acc[mi][ni], 0, 0, 0);
        }
      }
      ushort* ypp = yp + (size_t)cs * 2097152 + ((size_t)(b * 1024 + P0)) * 128;
#pragma unroll
      for (int mi = 0; mi < 2; ++mi) {
#pragma unroll
        for (int r = 0; r < 4; ++r) {
          int m = m_w + mi * 16 + quad * 4 + r;
          ushort* orow = ypp + (size_t)m * 128;
#pragma unroll
          for (int ni = 0; ni < 4; ++ni)
            orow[n_w + ni * 16 + lr] = f2bf(acc[mi][ni][r]);
        }
      }
      __syncthreads();
    }
  }
  gbar(&ctr[1], 512);

  // ===== phase 3: yred (512 units of 32 rows) =====
  {
    int oc = tid & 127, rh = tid >> 7;
    float bias = b_dcn[oc];
    float s = 0.f, sq = 0.f;
    int r0 = blk * 32;
    for (int r = rh; r < 32; r += 2) {
      size_t idx = ((size_t)(r0 + r)) * 128 + oc;
      float v = b2f(yp[idx]) + b2f(yp[2097152 + idx]) + b2f(yp[4194304 + idx])
              + b2f(yp[6291456 + idx]) + bias;
      ysum[idx] = f2bf(v);
      s += v; sq = fmaf(v, v, sq);
    }
    float* ls = (float*)smem;
    float* lq = ls + 256;
    ls[tid] = s; lq[tid] = sq; __syncthreads();
    if (tid < 128) {
      float* dst = st1 + (blk & 7) * 256;
      atomicAdd(&dst[tid], ls[tid] + ls[tid + 128]);
      atomicAdd(&dst[128 + tid], lq[tid] + lq[tid + 128]);
    }
  }
  gbar(&ctr[2], 512);

  // ===== phase 4: ybn (2 units) =====
  {
    if (tid < 128) {
      float s = 0.f, sq = 0.f;
#pragma unroll
      for (int c = 0; c < 8; ++c) {
        s += st1[c * 256 + tid];
        sq += st1[c * 256 + 128 + tid];
      }
      float mean = s / 16384.f;
      float var = sq / 16384.f - mean * mean;
      float sc = g1[tid] * rsqrtf(var + EPSV);
      scsS[tid] = sc;
      shsS[tid] = fmaf(-mean, sc, bt1[tid]);
    }
    __syncthreads();
    for (int u = 0; u < 2; ++u) {
      int i8 = (blk * 2 + u) * 256 + tid;
      size_t i = (size_t)i8 * 8;
      int oc = (int)(i & 127);
      uint4 pv = *(const uint4*)(ysum + i);
      uint words[4] = {pv.x, pv.y, pv.z, pv.w};
      uint owords[4];
#pragma unroll
      for (int j = 0; j < 4; ++j) {
        ushort u0 = (ushort)(words[j] & 0xFFFFu);
        ushort u1 = (ushort)(words[j] >> 16);
        int c0 = oc + 2 * j, c1 = oc + 2 * j + 1;
        float v0 = fmaxf(fmaf(b2f(u0), scsS[c0], shsS[c0]), 0.f);
        float v1 = fmaxf(fmaf(b2f(u1), scsS[c1], shsS[c1]), 0.f);
        owords[j] = (uint)f2bf(v0) | ((uint)f2bf(v1) << 16);
      }
      *(uint4*)(ybn + i) = make_uint4(owords[0], owords[1], owords[2], owords[3]);
    }
  }
  gbar(&ctr[3], 512);

  // ===== phase 5: deconv (2 units), barrier-free register GEMM =====
  {
    for (int u = 0; u < 2; ++u) {
      int ublk = blk * 2 + u;
      int pt = ublk & 15, par = (ublk >> 4) & 3, b = ublk >> 6;
      int pu = par >> 1, pv = par & 1;
      int P0 = pt * 64;
      int hh[4], ww[4];
#pragma unroll
      for (int mi = 0; mi < 4; ++mi) {
        int p = P0 + mi * 16 + lr;
        hh[mi] = p >> 5; ww[mi] = p & 31;
      }
      floatx4 acc[4][2];
#pragma unroll
      for (int mi = 0; mi < 4; ++mi)
#pragma unroll
        for (int ni = 0; ni < 2; ++ni) acc[mi][ni] = (floatx4)0.f;

      const ushort* ybb = ybn + (size_t)b * 1024 * 128;
      const ushort* bqb = bq + par * 65536 + quad * 1024 + (wid * 32 + lr) * 8;

#pragma unroll
      for (int tap = 0; tap < 4; ++tap) {
        int ty = tap >> 1, tx = tap & 1;
        int ab[4]; bool val[4];
#pragma unroll
        for (int mi = 0; mi < 4; ++mi) {
          int i = hh[mi] + pu - ty, j = ww[mi] + pv - tx;
          val[mi] = (i >= 0) && (i <= 31) && (j >= 0) && (j <= 31);
          int pos = min(max(i, 0), 31) * 32 + min(max(j, 0), 31);
          ab[mi] = pos * 128;
        }
#pragma unroll
        for (int k2 = 0; k2 < 4; ++k2) {
          int kstep = tap * 4 + k2;
          int c0 = k2 * 32 + quad * 8;
          short8 bf[2];
#pragma unroll
          for (int ni = 0; ni < 2; ++ni)
            bf[ni] = *(const short8*)(bqb + kstep * 4096 + ni * 128);
          short8 af[4];
#pragma unroll
          for (int mi = 0; mi < 4; ++mi) {
            short8 a = *(const short8*)(ybb + ab[mi] + c0);
            af[mi] = val[mi] ? a : (short8)0;
          }
#pragma unroll
          for (int mi = 0; mi < 4; ++mi)
#pragma unroll
            for (int ni = 0; ni < 2; ++ni)
              acc[mi][ni] = __builtin_amdgcn_mfma_f32_16x16x32_bf16(af[mi], bf[ni], acc[mi][ni], 0, 0, 0);
        }
      }
      size_t obase = (size_t)(b * 4 + par) * 1024 * 128;
#pragma unroll
      for (int mi = 0; mi < 4; ++mi) {
#pragma unroll
        for (int r = 0; r < 4; ++r) {
          int m = mi * 16 + quad * 4 + r;
          ushort* orow = Ob + obase + (size_t)(P0 + m) * 128 + wid * 32;
#pragma unroll
          for (int ni = 0; ni < 2; ++ni)
            orow[ni * 16 + lr] = f2bf(acc[mi][ni][r]);
        }
      }
      float sn[2], qn[2];
#pragma unroll
      for (int ni = 0; ni < 2; ++ni) {
        float s = 0.f, q = 0.f;
#pragma unroll
        for (int mi = 0; mi < 4; ++mi)
#pragma unroll
          for (int r = 0; r < 4; ++r) {
            float v = acc[mi][ni][r];
            s += v; q = fmaf(v, v, q);
          }
        sn[ni] = s; qn[ni] = q;
      }
#pragma unroll
      for (int ni = 0; ni < 2; ++ni) {
        sn[ni] += __shfl_xor(sn[ni], 16);
        sn[ni] += __shfl_xor(sn[ni], 32);
        qn[ni] += __shfl_xor(qn[ni], 16);
        qn[ni] += __shfl_xor(qn[ni], 32);
      }
      if (lane < 16) {
        float* dst = st2 + (ublk & 15) * 256;
#pragma unroll
        for (int ni = 0; ni < 2; ++ni) {
          atomicAdd(&dst[wid * 32 + ni * 16 + lr], sn[ni]);
          atomicAdd(&dst[128 + wid * 32 + ni * 16 + lr], qn[ni]);
        }
      }
    }
  }
  gbar(&ctr[4], 512);

  // ===== phase 6: bnout (4 units) =====
  {
    if (tid < 128) {
      float s = 0.f, sq = 0.f;
#pragma unroll
      for (int c = 0; c < 16; ++c) {
        s += st2[c * 256 + tid];
        sq += st2[c * 256 + 128 + tid];
      }
      float mean = s / 65536.f;
      float var = sq / 65536.f - mean * mean;
      float sc = g2[tid] * rsqrtf(var + EPSV);
      scsS[tid] = sc;
      shsS[tid] = fmaf(-mean, sc, bt2[tid]);
    }
    __syncthreads();
    float* tile = (float*)smem;   // 128 x 33
    for (int u = 0; u < 4; ++u) {
      int ublk = blk * 4 + u;
      int uu = ublk & 31, par = (ublk >> 5) & 3, b = ublk >> 7;
      int pu = par >> 1, pv = par & 1;
#pragma unroll 4
      for (int it = 0; it < 16; ++it) {
        int idx = it * 256 + tid;
        int vv = idx >> 7, oc = idx & 127;
        float v = b2f(Ob[((size_t)(b * 4 + par) * 1024 + uu * 32 + vv) * 128 + oc]);
        tile[oc * 33 + vv] = fmaxf(fmaf(v, scsS[oc], shsS[oc]), 0.f);
      }
      __syncthreads();
#pragma unroll 4
      for (int it = 0; it < 16; ++it) {
        int idx = it * 256 + tid;
        int oc = idx >> 5, vv = idx & 31;
        out[((size_t)b * 128 + oc) * 4096 + (2 * uu + pu) * 64 + 2 * vv + pv] = tile[oc * 33 + vv];
      }
      __syncthreads();
    }
  }
}

extern "C" void kernel_launch(void* const* d_in, const int* in_sizes, int n_in,
                              void* d_out, int out_size, void* d_ws, size_t ws_size,
                              hipStream_t stream) {
  const float* x     = (const float*)d_in[0];
  const float* w_off = (const float*)d_in[1];
  const float* b_off = (const float*)d_in[2];
  const float* w_dcn = (const float*)d_in[3];
  const float* b_dcn = (const float*)d_in[4];
  const float* g1    = (const float*)d_in[5];
  const float* bt1   = (const float*)d_in[6];
  const float* w_up  = (const float*)d_in[7];
  const float* g2    = (const float*)d_in[8];
  const float* bt2   = (const float*)d_in[9];
  float* ws  = (float*)d_ws;
  float* out = (float*)d_out;

  prep_xt_kernel<<<5561, 256, 0, stream>>>(x, w_off, w_dcn, w_up, ws);
  mega_kernel<<<512, 256, 0, stream>>>(b_off, b_dcn, g1, bt1, g2, bt2, ws, out);
}